// Round 15
// baseline (196.207 us; speedup 1.0000x reference)
//
#include <hip/hip_runtime.h>

#define NN 100000
#define NE 1600000
#define D 64

#define NBUCK ((NN + 255) / 256)              // 391 buckets of 256 nodes
#define EPB 4096                               // edges per partition block
#define P1_BLOCKS ((NE + EPB - 1) / EPB)       // 391
#define BCAP 6144                              // fixed bucket capacity (avg 4096, sigma 64)

#define F2BF_BLOCKS (NN * 16 / 256)            // 6250 (NN*16 float4 elems)
#define WPREP_BLOCKS (3 * 64 * 128 / 256)      // 96

typedef __attribute__((ext_vector_type(8))) short bfrag;   // 8 bf16 = 4 VGPR
typedef __attribute__((ext_vector_type(4))) float f4acc;   // 4 fp32 acc

__device__ __forceinline__ unsigned short f2bf(float f) {
    unsigned u = __float_as_uint(f);
    u = (u + 0x7FFFu + ((u >> 16) & 1u)) >> 16;  // RNE
    return (unsigned short)u;
}

// ---------------- p1 + prep fused: partition edges (blocks 0..P1_BLOCKS-1),
// f2bf(x) + weight concat (remaining blocks). bucket_cur pre-zeroed by memset.
__global__ __launch_bounds__(256) void p1prep_kernel(
    const int* __restrict__ src, const int* __restrict__ dst,
    int* __restrict__ bucket_cur, unsigned* __restrict__ packed,
    const float* __restrict__ x, unsigned short* __restrict__ xb,
    const float* __restrict__ Wl0, const float* __restrict__ Wr0,
    const float* __restrict__ Wl1, const float* __restrict__ Wr1,
    const float* __restrict__ Wl2, const float* __restrict__ Wr2,
    unsigned short* __restrict__ wcat) {
    int b = blockIdx.x;
    int t = threadIdx.x;
    if (b >= P1_BLOCKS) {
        int pb = b - P1_BLOCKS;
        if (pb < F2BF_BLOCKS) {
            int i = pb * 256 + t;  // < NN*16
            float4 v = ((const float4*)x)[i];
            ushort4 o;
            o.x = f2bf(v.x); o.y = f2bf(v.y); o.z = f2bf(v.z); o.w = f2bf(v.w);
            ((ushort4*)xb)[i] = o;
        } else {
            int i = (pb - F2BF_BLOCKS) * 256 + t;  // < 3*64*128
            int layer = i >> 13;
            int rem = i & 8191;
            int n = rem >> 7;
            int k = rem & 127;
            const float* W;
            if (layer == 0) W = (k < 64) ? Wl0 : Wr0;
            else if (layer == 1) W = (k < 64) ? Wl1 : Wr1;
            else W = (k < 64) ? Wl2 : Wr2;
            wcat[i] = f2bf(W[n * 64 + (k & 63)]);
        }
        return;
    }
    // ---- p1 partition ----
    __shared__ int h[NBUCK];            // hist, then per-bucket reserved global offset
    __shared__ int ls[512];             // padded inclusive scan
    __shared__ int lstart[NBUCK];       // local exclusive starts
    __shared__ int lcur[NBUCK];         // local cursors
    __shared__ unsigned sl[EPB];        // staged packed words (16 KB)
    __shared__ unsigned short sb[EPB];  // staged bucket ids (8 KB)
    for (int i = t; i < NBUCK; i += 256) h[i] = 0;
    __syncthreads();
    int base = b * EPB;
    int cnt = min(EPB, NE - base);
    for (int i = t; i < cnt; i += 256) atomicAdd(&h[dst[base + i] >> 8], 1);
    __syncthreads();
    ls[t] = h[t];
    ls[t + 256] = (t + 256 < NBUCK) ? h[t + 256] : 0;
    __syncthreads();
    for (int off = 1; off < 512; off <<= 1) {
        int a = (t >= off) ? ls[t - off] : 0;
        int b2 = (t + 256 >= off) ? ls[t + 256 - off] : 0;
        __syncthreads();
        ls[t] += a;
        ls[t + 256] += b2;
        __syncthreads();
    }
    for (int i = t; i < NBUCK; i += 256) {
        int c = h[i];
        int excl = ls[i] - c;
        lstart[i] = excl;
        lcur[i] = excl;
        h[i] = c ? atomicAdd(&bucket_cur[i], c) : 0;  // offset within bucket region
    }
    __syncthreads();
    for (int i = t; i < cnt; i += 256) {
        int d = dst[base + i];
        int bk = d >> 8;
        int pos = atomicAdd(&lcur[bk], 1);
        sl[pos] = ((unsigned)(d & 255) << 24) | (unsigned)src[base + i];
        sb[pos] = (unsigned short)bk;
    }
    __syncthreads();
    for (int j = t; j < cnt; j += 256) {
        int bk = sb[j];
        packed[bk * BCAP + h[bk] + (j - lstart[bk])] = sl[j];
    }
}

// p2b: per-bucket hist + scan -> rowpair; in-LDS sort -> esrc (+pad 16);
// degree-binned counting sort of node ids -> nodeperm (wave load balancing).
__global__ __launch_bounds__(256) void p2b_place(const unsigned* __restrict__ packed,
                                                 const int* __restrict__ bucket_cur,
                                                 int2* __restrict__ rowpair,
                                                 int* __restrict__ esrc,
                                                 int* __restrict__ nodeperm, int nNodes) {
    __shared__ int h[256];
    __shared__ int cur[256];
    __shared__ int sl[BCAP];
    __shared__ int dh[64];
    __shared__ int dls[64];
    __shared__ int dcur[64];
    int b = blockIdx.x, t = threadIdx.x;
    h[t] = 0;
    if (t < 64) dh[t] = 0;
    __syncthreads();
    int lo = b * BCAP;
    int cnt = bucket_cur[b];
    for (int i = t; i < cnt; i += 256) atomicAdd(&h[packed[lo + i] >> 24], 1);
    __syncthreads();
    int v = h[t];
    for (int off = 1; off < 256; off <<= 1) {
        int u = (t >= off) ? h[t - off] : 0;
        __syncthreads();
        h[t] += u;
        __syncthreads();
    }
    int incl = h[t];
    int excl = incl - v;
    cur[t] = excl;
    int node = b * 256 + t;
    bool valid = node < nNodes;
    int bin = min(v, 63);
    if (valid) {
        rowpair[node] = make_int2(lo + excl, lo + incl);  // never spans pad gap
        atomicAdd(&dh[bin], 1);
    }
    __syncthreads();
    // edge placement into sl
    for (int i = t; i < cnt; i += 256) {
        unsigned p = packed[lo + i];
        int pos = atomicAdd(&cur[p >> 24], 1);
        if (pos < BCAP) sl[pos] = (int)(p & 0xFFFFFFu);
    }
    // degree-bin scan (64 bins)
    if (t < 64) dls[t] = dh[t];
    __syncthreads();
    for (int off = 1; off < 64; off <<= 1) {
        int u = (t >= off && t < 64) ? dls[t - off] : 0;
        __syncthreads();
        if (t < 64) dls[t] += u;
        __syncthreads();
    }
    if (t < 64) dcur[t] = dls[t] - dh[t];
    __syncthreads();
    if (valid) {
        int pos = atomicAdd(&dcur[bin], 1);
        nodeperm[b * 256 + pos] = node;
    } else {
        nodeperm[b * 256 + t] = -1;  // invalid threads are exactly positions nv..255
    }
    for (int i = t; i < cnt; i += 256) esrc[lo + i] = sl[i];
    if (t < 16 && cnt + t < BCAP) esrc[lo + cnt + t] = 0;
}

// ---------------- fused layer: gather-mean (LDS) + MFMA dual-linear ----------------
// 256 threads = 32 nodes, taken in degree-sorted order via nodeperm (equal-degree
// waves -> no max-of-8 batch divergence). Phase 1: 8 lanes/node; 16-slot batches,
// clamped-dedup tail. Phase 2: 4 waves x (2 row-tiles, 16 cols) MFMA, K=128.
// Epilogue: acc -> swizzled LDS tile -> coalesced (per-row) global write.
__global__ __launch_bounds__(256) void sage_layer(
    const unsigned short* __restrict__ xb,   // gather table == root features
    const int2* __restrict__ rowpair, const int* __restrict__ esrc,
    const int* __restrict__ nodeperm,
    const unsigned short* __restrict__ wcat,  // [64][128] bf16, this layer
    const float* __restrict__ bl,
    float* __restrict__ outF,                 // final layer (else null)
    unsigned short* __restrict__ outB,        // hidden layers (else null)
    int nNodes, int doRelu) {
    __shared__ unsigned short smean[32 * 64];  // bf16 [row][col], col ^= (row&7)<<3
    __shared__ float tf[32 * 64];              // f32 epilogue tile (final layer)

    int t = threadIdx.x;
    int pbase = blockIdx.x * 32;
    // ---- phase 1: gather + mean ----
    {
        int nl = t >> 3;            // row local 0..31
        int q = t & 7;              // channel octet
        int lane = t & 63;
        int gbase = lane & 56;
        int node = nodeperm[pbase + nl];
        uint4 o = make_uint4(0, 0, 0, 0);
        if (node >= 0) {
            int2 rp = rowpair[node];
            int rs = rp.x;
            int re = rp.y;
            float a0 = 0, a1 = 0, a2 = 0, a3 = 0, a4 = 0, a5 = 0, a6 = 0, a7 = 0;
            for (int i = rs; i < re; i += 16) {
                int mA = esrc[i + q];       // slots 0..7   (coalesced per group)
                int mB = esrc[i + 8 + q];   // slots 8..15  (bucket padded by 16)
                int rem = re - i;           // uniform per 8-lane group, >0
                int s[16];
#pragma unroll
                for (int j = 0; j < 16; ++j) {
                    int jj = min(j, rem - 1);             // clamp: dup last valid edge
                    int sa = __shfl(mA, gbase + (jj & 7), 64);
                    int sb2 = __shfl(mB, gbase + (jj & 7), 64);
                    s[j] = (jj < 8) ? sa : sb2;
                }
#pragma unroll
                for (int j = 0; j < 16; ++j) {
                    uint4 w = ((const uint4*)xb)[s[j] * 8 + q];  // dup slots merge in L2
                    if (i + j < re) {
                        a0 += __uint_as_float(w.x << 16);
                        a1 += __uint_as_float(w.x & 0xFFFF0000u);
                        a2 += __uint_as_float(w.y << 16);
                        a3 += __uint_as_float(w.y & 0xFFFF0000u);
                        a4 += __uint_as_float(w.z << 16);
                        a5 += __uint_as_float(w.z & 0xFFFF0000u);
                        a6 += __uint_as_float(w.w << 16);
                        a7 += __uint_as_float(w.w & 0xFFFF0000u);
                    }
                }
            }
            float inv = 1.0f / fmaxf((float)(re - rs), 1.0f);
            o.x = (unsigned)f2bf(a0 * inv) | ((unsigned)f2bf(a1 * inv) << 16);
            o.y = (unsigned)f2bf(a2 * inv) | ((unsigned)f2bf(a3 * inv) << 16);
            o.z = (unsigned)f2bf(a4 * inv) | ((unsigned)f2bf(a5 * inv) << 16);
            o.w = (unsigned)f2bf(a6 * inv) | ((unsigned)f2bf(a7 * inv) << 16);
        }
        int idx = nl * 64 + ((q * 8) ^ ((nl & 7) << 3));  // swizzled, 16B aligned
        *(uint4*)&smean[idx] = o;
    }
    __syncthreads();

    // ---- phase 2: MFMA ----
    int w = t >> 6;    // wave 0..3 = col group
    int l = t & 63;
    int lr = l & 15;   // A row-in-tile / B col / C col
    int lk = l >> 4;   // k-group

    const bfrag* wB = (const bfrag*)wcat;  // 16 frags per 128-k row
    int n = w * 16 + lr;                   // output channel
    bfrag b0 = wB[n * 16 + lk];
    bfrag b1 = wB[n * 16 + 4 + lk];
    bfrag b2 = wB[n * 16 + 8 + lk];
    bfrag b3 = wB[n * 16 + 12 + lk];
    float bias = bl[n];

    f4acc accv[2];
#pragma unroll
    for (int rt = 0; rt < 2; ++rt) {
        int lrow = rt * 16 + lr;
        int sw = (lrow & 7) << 3;
        bfrag a0 = *(const bfrag*)&smean[lrow * 64 + ((lk * 8) ^ sw)];
        bfrag a1 = *(const bfrag*)&smean[lrow * 64 + ((32 + lk * 8) ^ sw)];
        int gnode = nodeperm[pbase + lrow];
        if (gnode < 0) gnode = 0;  // clamp (writes guarded in epilogue)
        const bfrag* xr = (const bfrag*)(xb + (size_t)gnode * D);
        bfrag a2 = xr[lk];
        bfrag a3 = xr[4 + lk];
        f4acc acc = {0.f, 0.f, 0.f, 0.f};
        acc = __builtin_amdgcn_mfma_f32_16x16x32_bf16(a0, b0, acc, 0, 0, 0);
        acc = __builtin_amdgcn_mfma_f32_16x16x32_bf16(a1, b1, acc, 0, 0, 0);
        acc = __builtin_amdgcn_mfma_f32_16x16x32_bf16(a2, b2, acc, 0, 0, 0);
        acc = __builtin_amdgcn_mfma_f32_16x16x32_bf16(a3, b3, acc, 0, 0, 0);
        accv[rt] = acc;
    }
    __syncthreads();  // smean reads done; tiles reusable

    // ---- epilogue: store via swizzled LDS tile (full-row writes) ----
    if (outB) {
#pragma unroll
        for (int rt = 0; rt < 2; ++rt)
#pragma unroll
            for (int r = 0; r < 4; ++r) {
                int row = rt * 16 + lk * 4 + r;  // 0..31
                float v = accv[rt][r] + bias;
                if (doRelu) v = fmaxf(v, 0.f);
                smean[row * 64 + (n ^ ((row & 7) << 3))] = f2bf(v);
            }
        __syncthreads();
        int row = t >> 3;
        int node = nodeperm[pbase + row];
        int c8 = t & 7;
        if (node >= 0) {
            uint4 v = *(uint4*)&smean[row * 64 + ((c8 ^ (row & 7)) * 8)];
            ((uint4*)outB)[(size_t)node * 8 + c8] = v;   // 128B per node row
        }
    } else {
#pragma unroll
        for (int rt = 0; rt < 2; ++rt)
#pragma unroll
            for (int r = 0; r < 4; ++r) {
                int row = rt * 16 + lk * 4 + r;
                float v = accv[rt][r] + bias;
                if (doRelu) v = fmaxf(v, 0.f);
                tf[row * 64 + (n ^ ((row & 7) << 3))] = v;
            }
        __syncthreads();
        int row = t >> 3;
        int node = nodeperm[pbase + row];
        int c8 = t & 7;
        if (node >= 0) {
            int cs = (c8 ^ (row & 7)) * 8;
            float4 v0 = *(float4*)&tf[row * 64 + cs];
            float4 v1 = *(float4*)&tf[row * 64 + cs + 4];
            ((float4*)outF)[(size_t)node * 16 + c8 * 2 + 0] = v0;  // 256B per node row
            ((float4*)outF)[(size_t)node * 16 + c8 * 2 + 1] = v1;
        }
    }
}

extern "C" void kernel_launch(void* const* d_in, const int* in_sizes, int n_in,
                              void* d_out, int out_size, void* d_ws, size_t ws_size,
                              hipStream_t stream) {
    const float* x   = (const float*)d_in[0];
    const int*   src = (const int*)d_in[1];
    const int*   dst = (const int*)d_in[2];
    const float* Wl0 = (const float*)d_in[3];
    const float* bl0 = (const float*)d_in[4];
    const float* Wr0 = (const float*)d_in[5];
    const float* Wl1 = (const float*)d_in[6];
    const float* bl1 = (const float*)d_in[7];
    const float* Wr1 = (const float*)d_in[8];
    const float* Wl2 = (const float*)d_in[9];
    const float* bl2 = (const float*)d_in[10];
    const float* Wr2 = (const float*)d_in[11];
    float* out = (float*)d_out;

    const size_t MB = 1 << 20;
    char* ws = (char*)d_ws;
    int* bucket_cur = (int*)(ws);                                  // NBUCK
    unsigned short* wcat = (unsigned short*)(ws + (128 << 10));    // 48 KB
    int2* rowpair = (int2*)(ws + 1 * MB);                          // NN int2 (800 KB)
    int* esrc   = (int*)(ws + 2 * MB);                             // NBUCK*BCAP (9.6 MB)
    int* nodeperm = (int*)(ws + 2 * MB + (size_t)NBUCK * BCAP * 4);  // NBUCK*256 ints (400 KB)
    unsigned* packed = (unsigned*)(ws + 13 * MB);                  // NBUCK*BCAP (9.6 MB, dead after p2b)
    unsigned short* hbA = (unsigned short*)(ws + 13 * MB);         // 12.8 MB (aliases packed)
    unsigned short* xb  = (unsigned short*)(ws + 27 * MB);         // 12.8 MB
    unsigned short* hbB = (unsigned short*)(ws + 40 * MB);         // 12.8 MB

    // zero bucket cursors (1.5 KB)
    hipMemsetAsync(bucket_cur, 0, (size_t)NBUCK * sizeof(int), stream);

    // ---- fused prep + partition ----
    p1prep_kernel<<<P1_BLOCKS + F2BF_BLOCKS + WPREP_BLOCKS, 256, 0, stream>>>(
        src, dst, bucket_cur, packed, x, xb, Wl0, Wr0, Wl1, Wr1, Wl2, Wr2, wcat);
    p2b_place<<<NBUCK, 256, 0, stream>>>(packed, bucket_cur, rowpair, esrc, nodeperm, NN);

    // ---- fused layers (grid spans nodeperm: NBUCK*256 slots, 32 per block) ----
    const int layerGrid = NBUCK * 8;
    sage_layer<<<layerGrid, 256, 0, stream>>>(xb,  rowpair, esrc, nodeperm, wcat,         bl0, nullptr, hbA, NN, 1);
    sage_layer<<<layerGrid, 256, 0, stream>>>(hbA, rowpair, esrc, nodeperm, wcat + 8192,  bl1, nullptr, hbB, NN, 1);
    sage_layer<<<layerGrid, 256, 0, stream>>>(hbB, rowpair, esrc, nodeperm, wcat + 16384, bl2, out, nullptr, NN, 0);
}

// Round 16
// 177.091 us; speedup vs baseline: 1.1079x; 1.1079x over previous
//
#include <hip/hip_runtime.h>

#define NN 100000
#define NE 1600000
#define D 64

#define NBUCK ((NN + 255) / 256)              // 391 buckets of 256 nodes
#define EPB 4096                               // edges per partition block
#define P1_BLOCKS ((NE + EPB - 1) / EPB)       // 391
#define BCAP 6144                              // fixed bucket capacity (avg 4096, sigma 64)

#define F2BF_BLOCKS (NN * 16 / 256)            // 6250 (NN*16 float4 elems)
#define WPREP_BLOCKS (3 * 64 * 128 / 256)      // 96

typedef __attribute__((ext_vector_type(8))) short bfrag;   // 8 bf16 = 4 VGPR
typedef __attribute__((ext_vector_type(4))) float f4acc;   // 4 fp32 acc

__device__ __forceinline__ unsigned short f2bf(float f) {
    unsigned u = __float_as_uint(f);
    u = (u + 0x7FFFu + ((u >> 16) & 1u)) >> 16;  // RNE
    return (unsigned short)u;
}

// ---------------- p1 + prep fused: partition edges (blocks 0..P1_BLOCKS-1),
// f2bf(x) + weight concat (remaining blocks). bucket_cur pre-zeroed by memset.
__global__ __launch_bounds__(256) void p1prep_kernel(
    const int* __restrict__ src, const int* __restrict__ dst,
    int* __restrict__ bucket_cur, unsigned* __restrict__ packed,
    const float* __restrict__ x, unsigned short* __restrict__ xb,
    const float* __restrict__ Wl0, const float* __restrict__ Wr0,
    const float* __restrict__ Wl1, const float* __restrict__ Wr1,
    const float* __restrict__ Wl2, const float* __restrict__ Wr2,
    unsigned short* __restrict__ wcat) {
    int b = blockIdx.x;
    int t = threadIdx.x;
    if (b >= P1_BLOCKS) {
        int pb = b - P1_BLOCKS;
        if (pb < F2BF_BLOCKS) {
            int i = pb * 256 + t;  // < NN*16
            float4 v = ((const float4*)x)[i];
            ushort4 o;
            o.x = f2bf(v.x); o.y = f2bf(v.y); o.z = f2bf(v.z); o.w = f2bf(v.w);
            ((ushort4*)xb)[i] = o;
        } else {
            int i = (pb - F2BF_BLOCKS) * 256 + t;  // < 3*64*128
            int layer = i >> 13;
            int rem = i & 8191;
            int n = rem >> 7;
            int k = rem & 127;
            const float* W;
            if (layer == 0) W = (k < 64) ? Wl0 : Wr0;
            else if (layer == 1) W = (k < 64) ? Wl1 : Wr1;
            else W = (k < 64) ? Wl2 : Wr2;
            wcat[i] = f2bf(W[n * 64 + (k & 63)]);
        }
        return;
    }
    // ---- p1 partition ----
    __shared__ int h[NBUCK];            // hist, then per-bucket reserved global offset
    __shared__ int ls[512];             // padded inclusive scan
    __shared__ int lstart[NBUCK];       // local exclusive starts
    __shared__ int lcur[NBUCK];         // local cursors
    __shared__ unsigned sl[EPB];        // staged packed words (16 KB)
    __shared__ unsigned short sb[EPB];  // staged bucket ids (8 KB)
    for (int i = t; i < NBUCK; i += 256) h[i] = 0;
    __syncthreads();
    int base = b * EPB;
    int cnt = min(EPB, NE - base);
    for (int i = t; i < cnt; i += 256) atomicAdd(&h[dst[base + i] >> 8], 1);
    __syncthreads();
    ls[t] = h[t];
    ls[t + 256] = (t + 256 < NBUCK) ? h[t + 256] : 0;
    __syncthreads();
    for (int off = 1; off < 512; off <<= 1) {
        int a = (t >= off) ? ls[t - off] : 0;
        int b2 = (t + 256 >= off) ? ls[t + 256 - off] : 0;
        __syncthreads();
        ls[t] += a;
        ls[t + 256] += b2;
        __syncthreads();
    }
    for (int i = t; i < NBUCK; i += 256) {
        int c = h[i];
        int excl = ls[i] - c;
        lstart[i] = excl;
        lcur[i] = excl;
        h[i] = c ? atomicAdd(&bucket_cur[i], c) : 0;  // offset within bucket region
    }
    __syncthreads();
    for (int i = t; i < cnt; i += 256) {
        int d = dst[base + i];
        int bk = d >> 8;
        int pos = atomicAdd(&lcur[bk], 1);
        sl[pos] = ((unsigned)(d & 255) << 24) | (unsigned)src[base + i];
        sb[pos] = (unsigned short)bk;
    }
    __syncthreads();
    for (int j = t; j < cnt; j += 256) {
        int bk = sb[j];
        packed[bk * BCAP + h[bk] + (j - lstart[bk])] = sl[j];
    }
}

// p2b: per-bucket hist + local scan -> rowpair(start,end); in-LDS sort -> esrc (+pad 16)
__global__ __launch_bounds__(256) void p2b_place(const unsigned* __restrict__ packed,
                                                 const int* __restrict__ bucket_cur,
                                                 int2* __restrict__ rowpair,
                                                 int* __restrict__ esrc, int nNodes) {
    __shared__ int h[256];
    __shared__ int cur[256];
    __shared__ int sl[BCAP];
    int b = blockIdx.x, t = threadIdx.x;
    h[t] = 0;
    __syncthreads();
    int lo = b * BCAP;
    int cnt = bucket_cur[b];
    for (int i = t; i < cnt; i += 256) atomicAdd(&h[packed[lo + i] >> 24], 1);
    __syncthreads();
    int v = h[t];
    for (int off = 1; off < 256; off <<= 1) {
        int u = (t >= off) ? h[t - off] : 0;
        __syncthreads();
        h[t] += u;
        __syncthreads();
    }
    int incl = h[t];
    int excl = incl - v;
    cur[t] = excl;
    int node = b * 256 + t;
    if (node < nNodes) rowpair[node] = make_int2(lo + excl, lo + incl);  // never spans pad gap
    __syncthreads();
    for (int i = t; i < cnt; i += 256) {
        unsigned p = packed[lo + i];
        int pos = atomicAdd(&cur[p >> 24], 1);
        if (pos < BCAP) sl[pos] = (int)(p & 0xFFFFFFu);
    }
    __syncthreads();
    for (int i = t; i < cnt; i += 256) esrc[lo + i] = sl[i];
    if (t < 16 && cnt + t < BCAP) esrc[lo + cnt + t] = 0;
}

// ---------------- fused layer: gather-mean (LDS) + MFMA dual-linear ----------------
// 256 threads = 32 nodes. Phase 1: 8 lanes/node; 16-slot batches, clamped-dedup tail.
// Phase 2: 4 waves x (2 row-tiles, 16 cols) MFMA over K=128 concat [mean | root].
// Epilogue: acc -> swizzled LDS tile (unioned with smean) -> coalesced global write.
__global__ __launch_bounds__(256) void sage_layer(
    const unsigned short* __restrict__ xb,   // gather table == root features
    const int2* __restrict__ rowpair, const int* __restrict__ esrc,
    const unsigned short* __restrict__ wcat,  // [64][128] bf16, this layer
    const float* __restrict__ bl,
    float* __restrict__ outF,                 // final layer (else null)
    unsigned short* __restrict__ outB,        // hidden layers (else null)
    int nNodes, int doRelu) {
    __shared__ union {
        unsigned short u16[32 * 64];  // bf16 mean tile / bf16 epilogue tile
        float f32[32 * 64];           // f32 epilogue tile (final layer)
    } s;
    unsigned short* smean = s.u16;

    int t = threadIdx.x;
    // ---- phase 1: gather + mean ----
    {
        int nl = t >> 3;            // node local 0..31
        int q = t & 7;              // channel octet
        int lane = t & 63;
        int gbase = lane & 56;
        int node = blockIdx.x * 32 + nl;
        uint4 o = make_uint4(0, 0, 0, 0);
        if (node < nNodes) {
            int2 rp = rowpair[node];
            int rs = rp.x;
            int re = rp.y;
            float a0 = 0, a1 = 0, a2 = 0, a3 = 0, a4 = 0, a5 = 0, a6 = 0, a7 = 0;
            for (int i = rs; i < re; i += 16) {
                int mA = esrc[i + q];       // slots 0..7   (coalesced per group)
                int mB = esrc[i + 8 + q];   // slots 8..15  (bucket padded by 16)
                int rem = re - i;           // uniform per 8-lane group, >0
                int sidx[16];
#pragma unroll
                for (int j = 0; j < 16; ++j) {
                    int jj = min(j, rem - 1);             // clamp: dup last valid edge
                    int sa = __shfl(mA, gbase + (jj & 7), 64);
                    int sb2 = __shfl(mB, gbase + (jj & 7), 64);
                    sidx[j] = (jj < 8) ? sa : sb2;
                }
#pragma unroll
                for (int j = 0; j < 16; ++j) {
                    uint4 w = ((const uint4*)xb)[sidx[j] * 8 + q];  // dup slots merge in L2
                    if (i + j < re) {
                        a0 += __uint_as_float(w.x << 16);
                        a1 += __uint_as_float(w.x & 0xFFFF0000u);
                        a2 += __uint_as_float(w.y << 16);
                        a3 += __uint_as_float(w.y & 0xFFFF0000u);
                        a4 += __uint_as_float(w.z << 16);
                        a5 += __uint_as_float(w.z & 0xFFFF0000u);
                        a6 += __uint_as_float(w.w << 16);
                        a7 += __uint_as_float(w.w & 0xFFFF0000u);
                    }
                }
            }
            float inv = 1.0f / fmaxf((float)(re - rs), 1.0f);
            o.x = (unsigned)f2bf(a0 * inv) | ((unsigned)f2bf(a1 * inv) << 16);
            o.y = (unsigned)f2bf(a2 * inv) | ((unsigned)f2bf(a3 * inv) << 16);
            o.z = (unsigned)f2bf(a4 * inv) | ((unsigned)f2bf(a5 * inv) << 16);
            o.w = (unsigned)f2bf(a6 * inv) | ((unsigned)f2bf(a7 * inv) << 16);
        }
        int idx = nl * 64 + ((q * 8) ^ ((nl & 7) << 3));  // swizzled, 16B aligned
        *(uint4*)&smean[idx] = o;
    }
    __syncthreads();

    // ---- phase 2: MFMA ----
    int w = t >> 6;    // wave 0..3 = col group
    int l = t & 63;
    int lr = l & 15;   // A row-in-tile / B col / C col
    int lk = l >> 4;   // k-group

    const bfrag* wB = (const bfrag*)wcat;  // 16 frags per 128-k row
    int n = w * 16 + lr;                   // output channel
    bfrag b0 = wB[n * 16 + lk];
    bfrag b1 = wB[n * 16 + 4 + lk];
    bfrag b2 = wB[n * 16 + 8 + lk];
    bfrag b3 = wB[n * 16 + 12 + lk];
    float bias = bl[n];

    int base = blockIdx.x * 32;
    f4acc accv[2];
#pragma unroll
    for (int rt = 0; rt < 2; ++rt) {
        int row0 = base + rt * 16;
        int lrow = rt * 16 + lr;
        int sw = (lrow & 7) << 3;
        bfrag a0 = *(const bfrag*)&smean[lrow * 64 + ((lk * 8) ^ sw)];
        bfrag a1 = *(const bfrag*)&smean[lrow * 64 + ((32 + lk * 8) ^ sw)];
        int grow = row0 + lr;
        if (grow >= nNodes) grow = nNodes - 1;  // clamp (writes guarded in epilogue)
        const bfrag* xr = (const bfrag*)(xb + (size_t)grow * D);
        bfrag a2 = xr[lk];
        bfrag a3 = xr[4 + lk];
        f4acc acc = {0.f, 0.f, 0.f, 0.f};
        acc = __builtin_amdgcn_mfma_f32_16x16x32_bf16(a0, b0, acc, 0, 0, 0);
        acc = __builtin_amdgcn_mfma_f32_16x16x32_bf16(a1, b1, acc, 0, 0, 0);
        acc = __builtin_amdgcn_mfma_f32_16x16x32_bf16(a2, b2, acc, 0, 0, 0);
        acc = __builtin_amdgcn_mfma_f32_16x16x32_bf16(a3, b3, acc, 0, 0, 0);
        accv[rt] = acc;
    }
    __syncthreads();  // smean reads done; tile reusable for epilogue

    // ---- epilogue: coalesced store via swizzled LDS tile ----
    if (outB) {
#pragma unroll
        for (int rt = 0; rt < 2; ++rt)
#pragma unroll
            for (int r = 0; r < 4; ++r) {
                int row = rt * 16 + lk * 4 + r;  // 0..31
                float v = accv[rt][r] + bias;
                if (doRelu) v = fmaxf(v, 0.f);
                smean[row * 64 + (n ^ ((row & 7) << 3))] = f2bf(v);
            }
        __syncthreads();
        int row = t >> 3;
        int node = base + row;
        int c8 = t & 7;
        if (node < nNodes) {
            uint4 v = *(uint4*)&smean[row * 64 + ((c8 ^ (row & 7)) * 8)];
            ((uint4*)outB)[(size_t)node * 8 + c8] = v;   // 16B coalesced
        }
    } else {
        float* tf = s.f32;
#pragma unroll
        for (int rt = 0; rt < 2; ++rt)
#pragma unroll
            for (int r = 0; r < 4; ++r) {
                int row = rt * 16 + lk * 4 + r;
                float v = accv[rt][r] + bias;
                if (doRelu) v = fmaxf(v, 0.f);
                tf[row * 64 + (n ^ ((row & 7) << 3))] = v;
            }
        __syncthreads();
        int row = t >> 3;
        int node = base + row;
        int c8 = t & 7;
        if (node < nNodes) {
            int cs = (c8 ^ (row & 7)) * 8;
            float4 v0 = *(float4*)&tf[row * 64 + cs];
            float4 v1 = *(float4*)&tf[row * 64 + cs + 4];
            ((float4*)outF)[(size_t)node * 16 + c8 * 2 + 0] = v0;  // 32B coalesced
            ((float4*)outF)[(size_t)node * 16 + c8 * 2 + 1] = v1;
        }
    }
}

extern "C" void kernel_launch(void* const* d_in, const int* in_sizes, int n_in,
                              void* d_out, int out_size, void* d_ws, size_t ws_size,
                              hipStream_t stream) {
    const float* x   = (const float*)d_in[0];
    const int*   src = (const int*)d_in[1];
    const int*   dst = (const int*)d_in[2];
    const float* Wl0 = (const float*)d_in[3];
    const float* bl0 = (const float*)d_in[4];
    const float* Wr0 = (const float*)d_in[5];
    const float* Wl1 = (const float*)d_in[6];
    const float* bl1 = (const float*)d_in[7];
    const float* Wr1 = (const float*)d_in[8];
    const float* Wl2 = (const float*)d_in[9];
    const float* bl2 = (const float*)d_in[10];
    const float* Wr2 = (const float*)d_in[11];
    float* out = (float*)d_out;

    const size_t MB = 1 << 20;
    char* ws = (char*)d_ws;
    int* bucket_cur = (int*)(ws);                                  // NBUCK
    unsigned short* wcat = (unsigned short*)(ws + (128 << 10));    // 48 KB
    int2* rowpair = (int2*)(ws + 1 * MB);                          // NN int2 (800 KB)
    int* esrc   = (int*)(ws + 2 * MB);                             // NBUCK*BCAP (9.6 MB)
    unsigned* packed = (unsigned*)(ws + 12 * MB);                  // NBUCK*BCAP (9.6 MB, dead after p2b)
    unsigned short* hbA = (unsigned short*)(ws + 12 * MB);         // 12.8 MB (aliases packed)
    unsigned short* xb  = (unsigned short*)(ws + 26 * MB);         // 12.8 MB
    unsigned short* hbB = (unsigned short*)(ws + 39 * MB);         // 12.8 MB

    // zero bucket cursors (1.5 KB — cheap; R7/R8 fill rows were harness poison)
    hipMemsetAsync(bucket_cur, 0, (size_t)NBUCK * sizeof(int), stream);

    // ---- fused prep + partition ----
    p1prep_kernel<<<P1_BLOCKS + F2BF_BLOCKS + WPREP_BLOCKS, 256, 0, stream>>>(
        src, dst, bucket_cur, packed, x, xb, Wl0, Wr0, Wl1, Wr1, Wl2, Wr2, wcat);
    p2b_place<<<NBUCK, 256, 0, stream>>>(packed, bucket_cur, rowpair, esrc, NN);

    // ---- fused layers ----
    const int layerGrid = (NN + 31) / 32;
    sage_layer<<<layerGrid, 256, 0, stream>>>(xb,  rowpair, esrc, wcat,         bl0, nullptr, hbA, NN, 1);
    sage_layer<<<layerGrid, 256, 0, stream>>>(hbA, rowpair, esrc, wcat + 8192,  bl1, nullptr, hbB, NN, 1);
    sage_layer<<<layerGrid, 256, 0, stream>>>(hbB, rowpair, esrc, wcat + 16384, bl2, out, nullptr, NN, 0);
}